// Round 5
// baseline (227.294 us; speedup 1.0000x reference)
//
#include <hip/hip_runtime.h>
#include <hip/hip_bf16.h>
#include <cstdint>

#define NN 2048
#define BB 8
#define DIN 128
#define DOUT 64
#define PHN 256            // n per phase in attn
#define NPH (NN / PHN)     // 8 phases
#define PCH 130            // shorts per P chunk-block: 16 rows * 8 + 2 pad

typedef __attribute__((ext_vector_type(8))) short bf16x8;
typedef __attribute__((ext_vector_type(4))) float f32x4;

static __device__ __forceinline__ unsigned short f2b(float f) {
    union { __hip_bfloat16 h; unsigned short s; } u;
    u.h = __float2bfloat16(f);
    return u.s;
}

// ---------------------------------------------------------------------------
// Kernel 1: xp = x@W^T + b via MFMA, K split across the 4 waves (unchanged
// from R4). grid = 1024 x 256. Epilogue emits bf16 xpT[b][d][n] + e_src/e_dst.
// ---------------------------------------------------------------------------
__global__ __launch_bounds__(256) void gat_xp_mfma(
    const float* __restrict__ x, const float* __restrict__ W,
    const float* __restrict__ bias, const float* __restrict__ a,
    unsigned short* __restrict__ xpT, float* __restrict__ e_src,
    float* __restrict__ e_dst)
{
    __shared__ float red[4 * 16 * 65];   // 16.6 KB
    const int t = threadIdx.x;
    const int lane = t & 63;
    const int w = t >> 6;
    const int lr = lane & 15;
    const int g  = lane >> 4;
    const int r0 = blockIdx.x * 16;
    const int k0 = w * 32 + g * 8;

    const float* xr = x + (size_t)(r0 + lr) * DIN + k0;
    const float4 xa = *(const float4*)xr;
    const float4 xb4 = *(const float4*)(xr + 4);
    bf16x8 afr;
    afr[0]=f2b(xa.x);  afr[1]=f2b(xa.y);  afr[2]=f2b(xa.z);  afr[3]=f2b(xa.w);
    afr[4]=f2b(xb4.x); afr[5]=f2b(xb4.y); afr[6]=f2b(xb4.z); afr[7]=f2b(xb4.w);

    #pragma unroll
    for (int dt = 0; dt < 4; ++dt) {
        const float* wr = W + (size_t)(dt * 16 + lr) * DIN + k0;
        const float4 wa = *(const float4*)wr;
        const float4 wb = *(const float4*)(wr + 4);
        bf16x8 bfr;
        bfr[0]=f2b(wa.x); bfr[1]=f2b(wa.y); bfr[2]=f2b(wa.z); bfr[3]=f2b(wa.w);
        bfr[4]=f2b(wb.x); bfr[5]=f2b(wb.y); bfr[6]=f2b(wb.z); bfr[7]=f2b(wb.w);
        f32x4 acc = {0.f, 0.f, 0.f, 0.f};
        acc = __builtin_amdgcn_mfma_f32_16x16x32_bf16(afr, bfr, acc, 0, 0, 0);
        #pragma unroll
        for (int reg = 0; reg < 4; ++reg)
            red[w * 1040 + (g * 4 + reg) * 65 + dt * 16 + lr] = acc[reg];
    }
    __syncthreads();

    const int row = t >> 4;
    const int dq  = t & 15;
    const int b   = r0 >> 11;
    const int nb  = r0 & (NN - 1);
    float es = 0.f, ed = 0.f;
    #pragma unroll
    for (int j = 0; j < 4; ++j) {
        const int d = dq * 4 + j;
        const float v = red[0 * 1040 + row * 65 + d] + red[1 * 1040 + row * 65 + d]
                      + red[2 * 1040 + row * 65 + d] + red[3 * 1040 + row * 65 + d]
                      + bias[d];
        es += v * a[d];
        ed += v * a[DOUT + d];
        xpT[((size_t)(b * DOUT + d) << 11) + nb + row] = f2b(v);
    }
    es += __shfl_xor(es, 1); es += __shfl_xor(es, 2);
    es += __shfl_xor(es, 4); es += __shfl_xor(es, 8);
    ed += __shfl_xor(ed, 1); ed += __shfl_xor(ed, 2);
    ed += __shfl_xor(ed, 4); ed += __shfl_xor(ed, 8);
    if (dq == 0) {
        e_src[r0 + row] = es;
        e_dst[r0 + row] = ed;
    }
}

// ---------------------------------------------------------------------------
// Kernel 2: fused masked-softmax + PV, counted-wait pipeline.
// Per phase: issue B-frags (this tile) + adj (tile+2) -> p-gen from adj
// loaded 2 phases ago -> ds_write P dbuf -> lgkmcnt(0)+raw s_barrier (vmcnt
// NOT drained; prefetches stay in flight) -> setprio(1) MFMA setprio(0).
// Single barrier/phase is race-free: writes of P[p&1] in phase p+2 are
// ordered after barrier p+1, which is after every wave's reads in phase p+1.
// ---------------------------------------------------------------------------
__global__ __launch_bounds__(256, 4) void gat_attn_mfma(
    const int* __restrict__ adj, const unsigned short* __restrict__ xpT,
    const float* __restrict__ e_src, const float* __restrict__ e_dst,
    float* __restrict__ out)
{
    __shared__ float d_lds[NN];                     // 8 KB
    __shared__ unsigned short p_lds[2][32 * PCH];   // 16.6 KB
    __shared__ float mred[4];
    __shared__ float s_lds[16];
    __shared__ float bnd_lds[16];
    __shared__ float rs_lds[16];

    const int t = threadIdx.x;
    const int lane = t & 63;
    const int w = t >> 6;
    const int lr = lane & 15;
    const int g  = lane >> 4;
    const int b  = blockIdx.x >> 7;
    const int m0 = (blockIdx.x & 127) * 16;
    const size_t base = (size_t)b * NN;

    // adj row pointers for this thread's 4 p-gen rows; issue tiles 0,1 now so
    // their HBM latency hides under the e_dst staging below.
    const int* aptr[4];
    #pragma unroll
    for (int it = 0; it < 4; ++it)
        aptr[it] = adj + ((base + (size_t)(m0 + it * 4 + w)) << 11) + lane * 4;

    int4 acur[4], amid[4], anew[4];
    #pragma unroll
    for (int it = 0; it < 4; ++it) acur[it] = *(const int4*)(aptr[it]);
    #pragma unroll
    for (int it = 0; it < 4; ++it) amid[it] = *(const int4*)(aptr[it] + PHN);

    // stage e_dst for the batch + per-batch max (softmax shift input)
    float dm = -1e30f;
    #pragma unroll
    for (int i = 0; i < 8; ++i) {
        const float v = e_dst[base + i * 256 + t];
        d_lds[i * 256 + t] = v;
        dm = fmaxf(dm, v);
    }
    #pragma unroll
    for (int off = 32; off >= 1; off >>= 1) dm = fmaxf(dm, __shfl_xor(dm, off));
    if (lane == 0) mred[w] = dm;
    __syncthreads();
    const float dmax = fmaxf(fmaxf(mred[0], mred[1]), fmaxf(mred[2], mred[3]));
    if (t < 16) {
        const float s = e_src[base + m0 + t];
        const float e0 = s + dmax;
        s_lds[t] = s;
        bnd_lds[t] = fmaxf(e0, 0.2f * e0);   // leaky(s+dmax) >= row max
    }
    __syncthreads();

    float srow[4], brow[4];
    #pragma unroll
    for (int it = 0; it < 4; ++it) {
        srow[it] = s_lds[it * 4 + w];
        brow[it] = bnd_lds[it * 4 + w];
    }

    f32x4 acc = {0.f, 0.f, 0.f, 0.f};
    float rs_acc[4] = {0.f, 0.f, 0.f, 0.f};
    const unsigned short* xb = xpT + ((size_t)(b * DOUT + w * 16 + lr) << 11);

    const int c  = lane >> 1;        // P chunk of this thread's 4 cols
    const int jj = (lane & 1) * 4;   // short offset within chunk row

    for (int ph = 0; ph < NPH; ++ph) {
        const int nb0 = ph * PHN;

        // 1. B-frags for THIS tile (consumed after the barrier; L2 latency
        //    hidden under p-gen).
        bf16x8 bfr[8];
        #pragma unroll
        for (int ks = 0; ks < 8; ++ks)
            bfr[ks] = *(const bf16x8*)(xb + nb0 + ks * 32 + g * 8);

        // 2. adj prefetch, 2 tiles ahead (stays in flight across barriers).
        if (ph + 2 < NPH) {
            #pragma unroll
            for (int it = 0; it < 4; ++it)
                anew[it] = *(const int4*)(aptr[it] + (ph + 2) * PHN);
        }

        // 3. p-gen from acur (loaded 2 phases ago -> no vmcnt stall).
        const float4 dv = *(const float4*)(d_lds + nb0 + lane * 4);
        const float dvv[4] = {dv.x, dv.y, dv.z, dv.w};
        unsigned short* pb = &p_lds[ph & 1][0];
        #pragma unroll
        for (int it = 0; it < 4; ++it) {
            const int row = it * 4 + w;
            const float s = srow[it], bd = brow[it];
            const int av[4] = {acur[it].x, acur[it].y, acur[it].z, acur[it].w};
            float p[4];
            #pragma unroll
            for (int j = 0; j < 4; ++j) {
                const float e = s + dvv[j];
                const float le = fmaxf(e, 0.2f * e);
                const float pe = __expf(le - bd);
                p[j] = av[j] ? pe : 0.f;
            }
            rs_acc[it] += (p[0] + p[1]) + (p[2] + p[3]);
            unsigned int* pp32 = (unsigned int*)(pb + c * PCH + row * 8 + jj);
            pp32[0] = ((unsigned)f2b(p[1]) << 16) | f2b(p[0]);
            pp32[1] = ((unsigned)f2b(p[3]) << 16) | f2b(p[2]);
        }

        // 4. counted-wait barrier: drain LDS writes only; vmcnt stays live.
        asm volatile("s_waitcnt lgkmcnt(0)" ::: "memory");
        __builtin_amdgcn_s_barrier();

        // 5. MFMA on the P tile (A from LDS: 4x ds_read_b32, bank
        //    (g+4*lr+j)%32 over 64 lanes = 2-way = free).
        const unsigned int* pw = (const unsigned int*)pb;
        __builtin_amdgcn_s_setprio(1);
        #pragma unroll
        for (int ks = 0; ks < 8; ++ks) {
            const int wbase = (ks * 4 + g) * 65 + lr * 4;
            union { unsigned int u[4]; bf16x8 v; } af;
            af.u[0] = pw[wbase + 0];
            af.u[1] = pw[wbase + 1];
            af.u[2] = pw[wbase + 2];
            af.u[3] = pw[wbase + 3];
            acc = __builtin_amdgcn_mfma_f32_16x16x32_bf16(af.v, bfr[ks], acc, 0, 0, 0);
        }
        __builtin_amdgcn_s_setprio(0);

        // 6. rotate adj pipeline.
        #pragma unroll
        for (int it = 0; it < 4; ++it) { acur[it] = amid[it]; amid[it] = anew[it]; }
    }

    // ---- row sums (reduce across the 64 lanes of each wave) ----
    #pragma unroll
    for (int it = 0; it < 4; ++it) {
        float v = rs_acc[it];
        #pragma unroll
        for (int off = 32; off >= 1; off >>= 1) v += __shfl_xor(v, off);
        if (lane == 0) rs_lds[it * 4 + w] = v;
    }
    __syncthreads();

    // ---- normalize + store: wave w owns cols [w*16, w*16+16) ----
    #pragma unroll
    for (int reg = 0; reg < 4; ++reg) {
        const int row = g * 4 + reg;
        const float o = acc[reg] / rs_lds[row];
        out[(base + (size_t)(m0 + row)) * DOUT + w * 16 + lr] = o;
    }
}

extern "C" void kernel_launch(void* const* d_in, const int* in_sizes, int n_in,
                              void* d_out, int out_size, void* d_ws, size_t ws_size,
                              hipStream_t stream) {
    const float* x    = (const float*)d_in[0];
    const int*   adj  = (const int*)d_in[1];
    const float* W    = (const float*)d_in[2];
    const float* bvec = (const float*)d_in[3];
    const float* a    = (const float*)d_in[4];
    float* out = (float*)d_out;

    unsigned short* xpT = (unsigned short*)d_ws;          // 2 MB bf16 [b][d][n]
    float* e_src = (float*)((char*)d_ws + (1 << 21));     // 64 KB
    float* e_dst = e_src + (size_t)BB * NN;               // 64 KB

    gat_xp_mfma<<<(BB * NN) / 16, 256, 0, stream>>>(x, W, bvec, a, xpT, e_src, e_dst);
    gat_attn_mfma<<<BB * (NN / 16), 256, 0, stream>>>(adj, xpT, e_src, e_dst, out);
}

// Round 6
// 216.527 us; speedup vs baseline: 1.0497x; 1.0497x over previous
//
#include <hip/hip_runtime.h>
#include <hip/hip_bf16.h>
#include <cstdint>

#define NN 2048
#define BB 8
#define DIN 128
#define DOUT 64
#define PHN 256            // n per phase in attn
#define NPH (NN / PHN)     // 8 phases
#define PCH 130            // shorts per P chunk-block: 16 rows * 8 + 2 pad

typedef __attribute__((ext_vector_type(8))) short bf16x8;
typedef __attribute__((ext_vector_type(4))) float f32x4;

static __device__ __forceinline__ unsigned short f2b(float f) {
    union { __hip_bfloat16 h; unsigned short s; } u;
    u.h = __float2bfloat16(f);
    return u.s;
}

// ---------------------------------------------------------------------------
// Kernel 1: xp = x@W^T + b via MFMA, K split across the 4 waves (unchanged).
// grid = 1024 x 256. Epilogue emits bf16 xpT[b][d][n] + e_src/e_dst.
// ---------------------------------------------------------------------------
__global__ __launch_bounds__(256) void gat_xp_mfma(
    const float* __restrict__ x, const float* __restrict__ W,
    const float* __restrict__ bias, const float* __restrict__ a,
    unsigned short* __restrict__ xpT, float* __restrict__ e_src,
    float* __restrict__ e_dst)
{
    __shared__ float red[4 * 16 * 65];   // 16.6 KB
    const int t = threadIdx.x;
    const int lane = t & 63;
    const int w = t >> 6;
    const int lr = lane & 15;
    const int g  = lane >> 4;
    const int r0 = blockIdx.x * 16;
    const int k0 = w * 32 + g * 8;

    const float* xr = x + (size_t)(r0 + lr) * DIN + k0;
    const float4 xa = *(const float4*)xr;
    const float4 xb4 = *(const float4*)(xr + 4);
    bf16x8 afr;
    afr[0]=f2b(xa.x);  afr[1]=f2b(xa.y);  afr[2]=f2b(xa.z);  afr[3]=f2b(xa.w);
    afr[4]=f2b(xb4.x); afr[5]=f2b(xb4.y); afr[6]=f2b(xb4.z); afr[7]=f2b(xb4.w);

    #pragma unroll
    for (int dt = 0; dt < 4; ++dt) {
        const float* wr = W + (size_t)(dt * 16 + lr) * DIN + k0;
        const float4 wa = *(const float4*)wr;
        const float4 wb = *(const float4*)(wr + 4);
        bf16x8 bfr;
        bfr[0]=f2b(wa.x); bfr[1]=f2b(wa.y); bfr[2]=f2b(wa.z); bfr[3]=f2b(wa.w);
        bfr[4]=f2b(wb.x); bfr[5]=f2b(wb.y); bfr[6]=f2b(wb.z); bfr[7]=f2b(wb.w);
        f32x4 acc = {0.f, 0.f, 0.f, 0.f};
        acc = __builtin_amdgcn_mfma_f32_16x16x32_bf16(afr, bfr, acc, 0, 0, 0);
        #pragma unroll
        for (int reg = 0; reg < 4; ++reg)
            red[w * 1040 + (g * 4 + reg) * 65 + dt * 16 + lr] = acc[reg];
    }
    __syncthreads();

    const int row = t >> 4;
    const int dq  = t & 15;
    const int b   = r0 >> 11;
    const int nb  = r0 & (NN - 1);
    float es = 0.f, ed = 0.f;
    #pragma unroll
    for (int j = 0; j < 4; ++j) {
        const int d = dq * 4 + j;
        const float v = red[0 * 1040 + row * 65 + d] + red[1 * 1040 + row * 65 + d]
                      + red[2 * 1040 + row * 65 + d] + red[3 * 1040 + row * 65 + d]
                      + bias[d];
        es += v * a[d];
        ed += v * a[DOUT + d];
        xpT[((size_t)(b * DOUT + d) << 11) + nb + row] = f2b(v);
    }
    es += __shfl_xor(es, 1); es += __shfl_xor(es, 2);
    es += __shfl_xor(es, 4); es += __shfl_xor(es, 8);
    ed += __shfl_xor(ed, 1); ed += __shfl_xor(ed, 2);
    ed += __shfl_xor(ed, 4); ed += __shfl_xor(ed, 8);
    if (dq == 0) {
        e_src[r0 + row] = es;
        e_dst[r0 + row] = ed;
    }
}

// ---------------------------------------------------------------------------
// Kernel 2: fused masked-softmax + PV, counted-wait pipeline.
// R6 change vs R5: __launch_bounds__(256, 2) instead of (256, 4). The (.,4)
// bound capped VGPR at 64 and spilled the pipeline state to scratch
// (R5 counters: VGPR=64, WRITE_SIZE 33MB vs 4.2MB of real output). The
// live state (adj depth-2 prefetch 48 + bfr 32 + acc/addr ~35) needs ~115
// regs; (.,2) caps at 256 so the allocator can keep it all resident.
// ---------------------------------------------------------------------------
__global__ __launch_bounds__(256, 2) void gat_attn_mfma(
    const int* __restrict__ adj, const unsigned short* __restrict__ xpT,
    const float* __restrict__ e_src, const float* __restrict__ e_dst,
    float* __restrict__ out)
{
    __shared__ float d_lds[NN];                     // 8 KB
    __shared__ unsigned short p_lds[2][32 * PCH];   // 16.6 KB
    __shared__ float mred[4];
    __shared__ float s_lds[16];
    __shared__ float bnd_lds[16];
    __shared__ float rs_lds[16];

    const int t = threadIdx.x;
    const int lane = t & 63;
    const int w = t >> 6;
    const int lr = lane & 15;
    const int g  = lane >> 4;
    const int b  = blockIdx.x >> 7;
    const int m0 = (blockIdx.x & 127) * 16;
    const size_t base = (size_t)b * NN;

    // adj row pointers for this thread's 4 p-gen rows; issue tiles 0,1 now so
    // their HBM latency hides under the e_dst staging below.
    const int* aptr[4];
    #pragma unroll
    for (int it = 0; it < 4; ++it)
        aptr[it] = adj + ((base + (size_t)(m0 + it * 4 + w)) << 11) + lane * 4;

    int4 acur[4], amid[4], anew[4];
    #pragma unroll
    for (int it = 0; it < 4; ++it) acur[it] = *(const int4*)(aptr[it]);
    #pragma unroll
    for (int it = 0; it < 4; ++it) amid[it] = *(const int4*)(aptr[it] + PHN);

    // stage e_dst for the batch + per-batch max (softmax shift input)
    float dm = -1e30f;
    #pragma unroll
    for (int i = 0; i < 8; ++i) {
        const float v = e_dst[base + i * 256 + t];
        d_lds[i * 256 + t] = v;
        dm = fmaxf(dm, v);
    }
    #pragma unroll
    for (int off = 32; off >= 1; off >>= 1) dm = fmaxf(dm, __shfl_xor(dm, off));
    if (lane == 0) mred[w] = dm;
    __syncthreads();
    const float dmax = fmaxf(fmaxf(mred[0], mred[1]), fmaxf(mred[2], mred[3]));
    if (t < 16) {
        const float s = e_src[base + m0 + t];
        const float e0 = s + dmax;
        s_lds[t] = s;
        bnd_lds[t] = fmaxf(e0, 0.2f * e0);   // leaky(s+dmax) >= row max
    }
    __syncthreads();

    float srow[4], brow[4];
    #pragma unroll
    for (int it = 0; it < 4; ++it) {
        srow[it] = s_lds[it * 4 + w];
        brow[it] = bnd_lds[it * 4 + w];
    }

    f32x4 acc = {0.f, 0.f, 0.f, 0.f};
    float rs_acc[4] = {0.f, 0.f, 0.f, 0.f};
    const unsigned short* xb = xpT + ((size_t)(b * DOUT + w * 16 + lr) << 11);

    const int c  = lane >> 1;        // P chunk of this thread's 4 cols
    const int jj = (lane & 1) * 4;   // short offset within chunk row

    for (int ph = 0; ph < NPH; ++ph) {
        const int nb0 = ph * PHN;

        // 1. B-frags for THIS tile (consumed after the barrier; L2 latency
        //    hidden under p-gen).
        bf16x8 bfr[8];
        #pragma unroll
        for (int ks = 0; ks < 8; ++ks)
            bfr[ks] = *(const bf16x8*)(xb + nb0 + ks * 32 + g * 8);

        // 2. adj prefetch, 2 tiles ahead (stays in flight across barriers).
        if (ph + 2 < NPH) {
            #pragma unroll
            for (int it = 0; it < 4; ++it)
                anew[it] = *(const int4*)(aptr[it] + (ph + 2) * PHN);
        }

        // 3. p-gen from acur (loaded 2 phases ago -> no vmcnt stall).
        const float4 dv = *(const float4*)(d_lds + nb0 + lane * 4);
        const float dvv[4] = {dv.x, dv.y, dv.z, dv.w};
        unsigned short* pb = &p_lds[ph & 1][0];
        #pragma unroll
        for (int it = 0; it < 4; ++it) {
            const int row = it * 4 + w;
            const float s = srow[it], bd = brow[it];
            const int av[4] = {acur[it].x, acur[it].y, acur[it].z, acur[it].w};
            float p[4];
            #pragma unroll
            for (int j = 0; j < 4; ++j) {
                const float e = s + dvv[j];
                const float le = fmaxf(e, 0.2f * e);
                const float pe = __expf(le - bd);
                p[j] = av[j] ? pe : 0.f;
            }
            rs_acc[it] += (p[0] + p[1]) + (p[2] + p[3]);
            unsigned int* pp32 = (unsigned int*)(pb + c * PCH + row * 8 + jj);
            pp32[0] = ((unsigned)f2b(p[1]) << 16) | f2b(p[0]);
            pp32[1] = ((unsigned)f2b(p[3]) << 16) | f2b(p[2]);
        }

        // 4. counted-wait barrier: drain LDS writes only; vmcnt stays live.
        asm volatile("s_waitcnt lgkmcnt(0)" ::: "memory");
        __builtin_amdgcn_s_barrier();

        // 5. MFMA on the P tile (A from LDS: 4x ds_read_b32, bank
        //    (g+4*lr+j)%32 over 64 lanes = 2-way = free).
        const unsigned int* pw = (const unsigned int*)pb;
        __builtin_amdgcn_s_setprio(1);
        #pragma unroll
        for (int ks = 0; ks < 8; ++ks) {
            const int wbase = (ks * 4 + g) * 65 + lr * 4;
            union { unsigned int u[4]; bf16x8 v; } af;
            af.u[0] = pw[wbase + 0];
            af.u[1] = pw[wbase + 1];
            af.u[2] = pw[wbase + 2];
            af.u[3] = pw[wbase + 3];
            acc = __builtin_amdgcn_mfma_f32_16x16x32_bf16(af.v, bfr[ks], acc, 0, 0, 0);
        }
        __builtin_amdgcn_s_setprio(0);

        // 6. rotate adj pipeline.
        #pragma unroll
        for (int it = 0; it < 4; ++it) { acur[it] = amid[it]; amid[it] = anew[it]; }
    }

    // ---- row sums (reduce across the 64 lanes of each wave) ----
    #pragma unroll
    for (int it = 0; it < 4; ++it) {
        float v = rs_acc[it];
        #pragma unroll
        for (int off = 32; off >= 1; off >>= 1) v += __shfl_xor(v, off);
        if (lane == 0) rs_lds[it * 4 + w] = v;
    }
    __syncthreads();

    // ---- normalize + store: wave w owns cols [w*16, w*16+16) ----
    #pragma unroll
    for (int reg = 0; reg < 4; ++reg) {
        const int row = g * 4 + reg;
        const float o = acc[reg] / rs_lds[row];
        out[(base + (size_t)(m0 + row)) * DOUT + w * 16 + lr] = o;
    }
}

extern "C" void kernel_launch(void* const* d_in, const int* in_sizes, int n_in,
                              void* d_out, int out_size, void* d_ws, size_t ws_size,
                              hipStream_t stream) {
    const float* x    = (const float*)d_in[0];
    const int*   adj  = (const int*)d_in[1];
    const float* W    = (const float*)d_in[2];
    const float* bvec = (const float*)d_in[3];
    const float* a    = (const float*)d_in[4];
    float* out = (float*)d_out;

    unsigned short* xpT = (unsigned short*)d_ws;          // 2 MB bf16 [b][d][n]
    float* e_src = (float*)((char*)d_ws + (1 << 21));     // 64 KB
    float* e_dst = e_src + (size_t)BB * NN;               // 64 KB

    gat_xp_mfma<<<(BB * NN) / 16, 256, 0, stream>>>(x, W, bvec, a, xpT, e_src, e_dst);
    gat_attn_mfma<<<BB * (NN / 16), 256, 0, stream>>>(adj, xpT, e_src, e_dst, out);
}